// Round 1
// 268.204 us; speedup vs baseline: 1.0702x; 1.0702x over previous
//
#include <hip/hip_runtime.h>
#include <math.h>

// Problem constants (fixed by the reference)
#define BB    4
#define TT    1024
#define EE    1024
#define HH    16
#define HDIM  64
#define SS    2048            // T * MULT
#define MROWS 4096            // B * T
// Q scale with log2(e) folded in: softmax runs in exp2 domain.
#define QSCALE 0.18033688011112f   // 0.125 * log2(e)
#define LOG2E  1.4426950408889634f

typedef short  s8v  __attribute__((ext_vector_type(8)));   // 8 bf16 (4 VGPRs)
typedef float  f4v  __attribute__((ext_vector_type(4)));   // 4 fp32 acc

__device__ __forceinline__ unsigned short f2bf(float f) {
    union { float f; unsigned u; } c; c.f = f;
    unsigned u = c.u + 0x7FFFu + ((c.u >> 16) & 1u);   // RNE
    return (unsigned short)(u >> 16);
}
__device__ __forceinline__ float bflo(unsigned u) {
    union { unsigned u; float f; } c; c.u = u << 16; return c.f;
}
__device__ __forceinline__ float bfhi(unsigned u) {
    union { unsigned u; float f; } c; c.u = u & 0xffff0000u; return c.f;
}

// async global->LDS, 16B per lane. LDS dest = wave-uniform base + lane*16.
__device__ __forceinline__ void async16(const void* g, void* l) {
    __builtin_amdgcn_global_load_lds(
        (const __attribute__((address_space(1))) unsigned int*)g,
        (__attribute__((address_space(3))) unsigned int*)l,
        16, 0, 0);
}

// ---------------------------------------------------------------------------
// Fused fp32->bf16 convert: x, Wq, Wk, Wv, Wo, mask in one launch.
// Mask is additionally scaled by log2(e) (softmax runs in exp2 domain).
// ---------------------------------------------------------------------------
__global__ __launch_bounds__(256) void cvt6_kernel(
    const float* __restrict__ x,  const float* __restrict__ wq,
    const float* __restrict__ wk, const float* __restrict__ wv,
    const float* __restrict__ wo, const float* __restrict__ mk,
    unsigned short* __restrict__ xb,  unsigned short* __restrict__ wqb,
    unsigned short* __restrict__ wkb, unsigned short* __restrict__ wvb,
    unsigned short* __restrict__ wob, unsigned short* __restrict__ mbb)
{
    const int total = 3670016;
    int i = blockIdx.x * 256 + threadIdx.x;
    const int stride = gridDim.x * 256;
    for (; i < total; i += stride) {
        const float* s; unsigned short* d; int off; float sc = 1.0f;
        if (i < 1048576)      { s = x;  d = xb;  off = i; }
        else if (i < 1310720) { s = wq; d = wqb; off = i - 1048576; }
        else if (i < 1835008) { s = wk; d = wkb; off = i - 1310720; }
        else if (i < 2359296) { s = wv; d = wvb; off = i - 1835008; }
        else if (i < 2621440) { s = wo; d = wob; off = i - 2359296; }
        else                  { s = mk; d = mbb; off = i - 2621440; sc = LOG2E; }
        float4 v = ((const float4*)s)[off];
        ushort4 o;
        o.x = f2bf(v.x * sc); o.y = f2bf(v.y * sc);
        o.z = f2bf(v.z * sc); o.w = f2bf(v.w * sc);
        ((ushort4*)d)[off] = o;
    }
}

// ---------------------------------------------------------------------------
// Shared GEMM K-loop body (m97-style): 128x128 tile, BK=32, global_load_lds
// width=16 into unpadded LDS [128][32] ushort (64B rows), 2 barriers/iter.
// ---------------------------------------------------------------------------
#define GEMM_KLOOP(Aptr, Wptr, Ksz)                                            \
    for (int k0 = 0; k0 < (Ksz); k0 += 32) {                                   \
        _Pragma("unroll")                                                      \
        for (int it = 0; it < 2; ++it) {                                       \
            int f = (it * 4 + w) * 64 + lane;                                  \
            int r = f >> 2, g = (f & 3) * 8;                                   \
            async16((Aptr) + (size_t)(m0 + r) * (Ksz) + k0 + g,                \
                    As + (it * 4 + w) * 512);                                  \
            async16((Wptr) + (size_t)(n0 + r) * (Ksz) + k0 + g,                \
                    Bs + (it * 4 + w) * 512);                                  \
        }                                                                      \
        __syncthreads();                                                       \
        s8v af[4], bf[4];                                                      \
        _Pragma("unroll")                                                      \
        for (int i = 0; i < 4; ++i)                                            \
            af[i] = *(const s8v*)(As + (wm + i * 16 + col16) * 32 + quad * 8); \
        _Pragma("unroll")                                                      \
        for (int j = 0; j < 4; ++j)                                            \
            bf[j] = *(const s8v*)(Bs + (wn + j * 16 + col16) * 32 + quad * 8); \
        _Pragma("unroll")                                                      \
        for (int i = 0; i < 4; ++i)                                            \
            _Pragma("unroll")                                                  \
            for (int j = 0; j < 4; ++j)                                        \
                acc[i][j] = __builtin_amdgcn_mfma_f32_16x16x32_bf16(           \
                    af[i], bf[j], acc[i][j], 0, 0, 0);                         \
        __syncthreads();                                                       \
    }

// ---------------------------------------------------------------------------
// Fused Q+K projection: A=x [4096,1024]; blockIdx.y<8 -> Q (scale by
// SCALE*log2e, bf16 into qp), else -> K (head layout into kp). Grid (32, 24).
// ---------------------------------------------------------------------------
__global__ __launch_bounds__(256, 3) void gemm_qk_kernel(
    const unsigned short* __restrict__ X,  const unsigned short* __restrict__ Wq,
    const unsigned short* __restrict__ Wk, const float* __restrict__ bq,
    const float* __restrict__ bk, unsigned short* __restrict__ qp,
    unsigned short* __restrict__ kp)
{
    __shared__ __align__(16) unsigned short As[128 * 32];
    __shared__ __align__(16) unsigned short Bs[128 * 32];

    const int tid = threadIdx.x;
    const int lane = tid & 63, w = tid >> 6;
    const int wm = (w & 1) * 64, wn = (w >> 1) * 64;
    const int col16 = lane & 15, quad = lane >> 4;
    const int m0 = blockIdx.x * 128;
    const bool isQ = blockIdx.y < 8;
    const int n0 = blockIdx.y * 128;
    const unsigned short* Wrow = isQ ? Wq + (size_t)n0 * EE
                                     : Wk + (size_t)(n0 - EE) * EE;

    f4v acc[4][4];
#pragma unroll
    for (int i = 0; i < 4; ++i)
#pragma unroll
        for (int j = 0; j < 4; ++j) acc[i][j] = (f4v)0.0f;

    for (int k0 = 0; k0 < EE; k0 += 32) {
#pragma unroll
        for (int it = 0; it < 2; ++it) {
            int f = (it * 4 + w) * 64 + lane;
            int r = f >> 2, g = (f & 3) * 8;
            async16(X + (size_t)(m0 + r) * EE + k0 + g, As + (it * 4 + w) * 512);
            async16(Wrow + (size_t)r * EE + k0 + g, Bs + (it * 4 + w) * 512);
        }
        __syncthreads();
        s8v af[4], bf[4];
#pragma unroll
        for (int i = 0; i < 4; ++i)
            af[i] = *(const s8v*)(As + (wm + i * 16 + col16) * 32 + quad * 8);
#pragma unroll
        for (int j = 0; j < 4; ++j)
            bf[j] = *(const s8v*)(Bs + (wn + j * 16 + col16) * 32 + quad * 8);
#pragma unroll
        for (int i = 0; i < 4; ++i)
#pragma unroll
            for (int j = 0; j < 4; ++j)
                acc[i][j] = __builtin_amdgcn_mfma_f32_16x16x32_bf16(
                    af[i], bf[j], acc[i][j], 0, 0, 0);
        __syncthreads();
    }

#pragma unroll
    for (int j = 0; j < 4; ++j) {
        const int n = n0 + wn + j * 16 + col16;           // global n in [0,3072)
        const float bn = isQ ? bq[n] : bk[n - EE];
#pragma unroll
        for (int i = 0; i < 4; ++i) {
            const int mb = m0 + wm + i * 16 + quad * 4;
#pragma unroll
            for (int r = 0; r < 4; ++r) {
                const int m = mb + r;
                float c = acc[i][j][r] + bn;
                if (isQ) {
                    qp[(size_t)m * EE + n] = f2bf(c * QSCALE);
                } else {
                    const int nk = n - EE;
                    const int mm = nk >> 10, h = (nk >> 6) & 15, d = nk & 63;
                    const int b_ = m >> 10, t = m & 1023;
                    const int s = 2 * t + mm;
                    kp[((size_t)(b_ * HH + h) * SS + s) * HDIM + d] = f2bf(c);
                }
            }
        }
    }
}

// ---------------------------------------------------------------------------
// General GEMM C = alpha*(A @ W^T + bias):
//   LAYOUT 0: plain C[m*Nsz+n] (OUTF32 picks fp32/bf16)
//   LAYOUT 2: V^T: A=Wv (rows f), W=x (rows token); writes [B,H,HD,S] bf16,
//             bias indexed by row m (=f).
// ---------------------------------------------------------------------------
template <int LAYOUT, int OUTF32, int Ksz, int Nsz>
__global__ __launch_bounds__(256, 3) void gemm_mfma_kernel(
    const unsigned short* __restrict__ A, const unsigned short* __restrict__ W,
    const float* __restrict__ bias, void* __restrict__ Cout, float alpha)
{
    __shared__ __align__(16) unsigned short As[128 * 32];
    __shared__ __align__(16) unsigned short Bs[128 * 32];

    const int tid = threadIdx.x;
    const int lane = tid & 63, w = tid >> 6;
    const int wm = (w & 1) * 64, wn = (w >> 1) * 64;
    const int col16 = lane & 15, quad = lane >> 4;
    const int m0 = blockIdx.x * 128;
    const int n0 = blockIdx.y * 128;

    f4v acc[4][4];
#pragma unroll
    for (int i = 0; i < 4; ++i)
#pragma unroll
        for (int j = 0; j < 4; ++j) acc[i][j] = (f4v)0.0f;

    GEMM_KLOOP(A, W, Ksz)

#pragma unroll
    for (int j = 0; j < 4; ++j) {
        const int n = n0 + wn + j * 16 + col16;
        const float bn = (LAYOUT == 2) ? 0.0f : bias[n];
#pragma unroll
        for (int i = 0; i < 4; ++i) {
            const int mb = m0 + wm + i * 16 + quad * 4;
#pragma unroll
            for (int r = 0; r < 4; ++r) {
                const int m = mb + r;
                float c = (acc[i][j][r] + ((LAYOUT == 2) ? bias[m] : bn)) * alpha;
                if (LAYOUT == 0) {
                    if (OUTF32) ((float*)Cout)[(size_t)m * Nsz + n] = c;
                    else ((unsigned short*)Cout)[(size_t)m * Nsz + n] = f2bf(c);
                } else {  // LAYOUT 2: m = feature f, n = token
                    const int mm = m >> 10, h = (m >> 6) & 15, d = m & 63;
                    const int b_ = n >> 10, t = n & 1023;
                    const int s = 2 * t + mm;
                    ((unsigned short*)Cout)[((size_t)(b_ * HH + h) * HDIM + d) * SS + s] = f2bf(c);
                }
            }
        }
    }
}

// ---------------------------------------------------------------------------
// Flash attention v3: bf16 MFMA, S^T formulation, MULT-paired s-tiles.
//  - Q held in registers (each wave only reads its own 16 t-rows)
//  - mask read direct from global (bf16, pre-scaled by log2e, L2-resident
//    via XCD swizzle) and folded into the S-MFMA C-operand (free add)
//  - exp2-domain softmax (log2e folded into Q scale + mask)
//  - defer-max (T13): skip cross-quad max shuffles + O rescale unless
//    __all(tmax - mrun <= 10); row-sum kept as per-lane f4v partial,
//    reduced once in the epilogue
//  - P packed with v_cvt_pk_bf16_f32 before barrier C (T12 primitive)
// LDS: 4 x (64x68) bf16 = 34.8 KB -> 4 blocks/CU; grid 1024 = 4*256 fully
// resident in ONE round (kills the 25%-occupancy residency tail).
// ---------------------------------------------------------------------------
__global__ __launch_bounds__(256, 4) void attn_mfma3_kernel(
    const unsigned short* __restrict__ Q, const unsigned short* __restrict__ Kh,
    const unsigned short* __restrict__ Vt, const unsigned short* __restrict__ Mb,
    unsigned short* __restrict__ O)
{
    constexpr int PT = 68;   // 136B pitch: conflict-free b128/b64 patterns
    __shared__ __align__(16) unsigned short K0[64 * PT];  // K half0, then P0
    __shared__ __align__(16) unsigned short K1[64 * PT];  // K half1, then P1
    __shared__ __align__(16) unsigned short V0[64 * PT];  // V^T half0 [d][s]
    __shared__ __align__(16) unsigned short V1[64 * PT];  // V^T half1 [d][s]

    const int tid = threadIdx.x;
    const int lane = tid & 63, w = tid >> 6;
    const int col16 = lane & 15, quad = lane >> 4;

    // XCD swizzle: v = gid&7 (virtual XCD), bh = v*8 + (j>>4), t0 = (j&15)*64
    const int gid = blockIdx.x;
    const int v = gid & 7, j = gid >> 3;
    const int bh = v * 8 + (j >> 4);
    const int t0 = (j & 15) * 64;
    const int b_ = bh >> 4, h = bh & 15;

    // Q fragments in registers: this lane's t-row = w*16+col16, k-slices
    const unsigned short* Qrow =
        Q + (size_t)(b_ * TT + t0 + w * 16 + col16) * EE + h * HDIM;
    const s8v qf0 = *(const s8v*)(Qrow + quad * 8);
    const s8v qf1 = *(const s8v*)(Qrow + 32 + quad * 8);

    f4v oacc[4];
#pragma unroll
    for (int jd = 0; jd < 4; ++jd) oacc[jd] = (f4v)0.0f;
    float mrun = -INFINITY;
    f4v l4 = (f4v)0.0f;           // per-lane partial row-sum (4 s-slots)

    const unsigned short* Kb   = Kh + (size_t)bh * SS * HDIM;
    const unsigned short* Vb   = Vt + (size_t)bh * HDIM * SS;
    const unsigned short* Mrow = Mb + (size_t)b_ * TT * TT
                               + (size_t)(t0 + w * 16 + col16) * TT;
    const int myrow = (w * 16 + col16) * PT;   // this lane's t-row in LDS

    for (int it16 = 0; it16 < 16; ++it16) {
        const int t2b = it16 * 64;

        // mask loads early (global, L2): mask[t][t2b + js*16 + quad*4 ..+3]
        uint2 mm[4];
#pragma unroll
        for (int js = 0; js < 4; ++js)
            mm[js] = *(const uint2*)(Mrow + t2b + js * 16 + quad * 4);

        __syncthreads();  // (A) prev iteration's PV reads done
#pragma unroll
        for (int st = 0; st < 2; ++st) {
            int idx = tid + st * 256;
            int r = idx >> 3, c = (idx & 7) * 8;
            *(uint4*)(K0 + r * PT + c) = *(const uint4*)(Kb + (size_t)(t2b + r) * HDIM + c);
            *(uint4*)(K1 + r * PT + c) = *(const uint4*)(Kb + (size_t)(1024 + t2b + r) * HDIM + c);
            *(uint4*)(V0 + r * PT + c) = *(const uint4*)(Vb + (size_t)r * SS + t2b + c);
            *(uint4*)(V1 + r * PT + c) = *(const uint4*)(Vb + (size_t)r * SS + 1024 + t2b + c);
        }
        __syncthreads();  // (B)

        // S^T halves: A=K (m=s), B=Q (n=t). C-in = mask (free add).
        f4v s0acc[4], s1acc[4];
#pragma unroll
        for (int js = 0; js < 4; ++js) {
            f4v mv;
            mv[0] = bflo(mm[js].x); mv[1] = bfhi(mm[js].x);
            mv[2] = bflo(mm[js].y); mv[3] = bfhi(mm[js].y);
            s0acc[js] = mv; s1acc[js] = mv;
        }
#pragma unroll
        for (int ks = 0; ks < 2; ++ks) {
            const s8v bq_ = ks ? qf1 : qf0;
#pragma unroll
            for (int js = 0; js < 4; ++js) {
                s8v ak0 = *(const s8v*)(K0 + (js * 16 + col16) * PT + ks * 32 + quad * 8);
                s8v ak1 = *(const s8v*)(K1 + (js * 16 + col16) * PT + ks * 32 + quad * 8);
                s0acc[js] = __builtin_amdgcn_mfma_f32_16x16x32_bf16(ak0, bq_, s0acc[js], 0, 0, 0);
                s1acc[js] = __builtin_amdgcn_mfma_f32_16x16x32_bf16(ak1, bq_, s1acc[js], 0, 0, 0);
            }
        }

        // per-lane max over this lane's 32 S values (max3-friendly tree)
        float tm0 = fmaxf(fmaxf(s0acc[0][0], s0acc[0][1]), fmaxf(s0acc[0][2], s0acc[0][3]));
        float tm1 = fmaxf(fmaxf(s0acc[1][0], s0acc[1][1]), fmaxf(s0acc[1][2], s0acc[1][3]));
        float tm2 = fmaxf(fmaxf(s0acc[2][0], s0acc[2][1]), fmaxf(s0acc[2][2], s0acc[2][3]));
        float tm3 = fmaxf(fmaxf(s0acc[3][0], s0acc[3][1]), fmaxf(s0acc[3][2], s0acc[3][3]));
        float tn0 = fmaxf(fmaxf(s1acc[0][0], s1acc[0][1]), fmaxf(s1acc[0][2], s1acc[0][3]));
        float tn1 = fmaxf(fmaxf(s1acc[1][0], s1acc[1][1]), fmaxf(s1acc[1][2], s1acc[1][3]));
        float tn2 = fmaxf(fmaxf(s1acc[2][0], s1acc[2][1]), fmaxf(s1acc[2][2], s1acc[2][3]));
        float tn3 = fmaxf(fmaxf(s1acc[3][0], s1acc[3][1]), fmaxf(s1acc[3][2], s1acc[3][3]));
        float tmax = fmaxf(fmaxf(fmaxf(tm0, tm1), fmaxf(tm2, tm3)),
                           fmaxf(fmaxf(tn0, tn1), fmaxf(tn2, tn3)));

        // defer-max: rescale only if some lane's max grew past mrun + 10
        if (!__all(tmax - mrun <= 10.0f)) {
            float tfull = fmaxf(tmax, __shfl_xor(tmax, 16));
            tfull = fmaxf(tfull, __shfl_xor(tfull, 32));
            const float mnew = fmaxf(mrun, tfull);
            const float scl = __builtin_amdgcn_exp2f(mrun - mnew);  // 0 on 1st
            l4 *= scl;
            float sclr[4];
#pragma unroll
            for (int r = 0; r < 4; ++r) sclr[r] = __shfl(scl, quad * 4 + r);
#pragma unroll
            for (int jd = 0; jd < 4; ++jd)
#pragma unroll
                for (int r = 0; r < 4; ++r) oacc[jd][r] *= sclr[r];
            mrun = mnew;
        }

        // exp2 + pack to bf16 (pre-barrier-C; only stores go after C)
        unsigned pk0[8], pk1[8];
#pragma unroll
        for (int js = 0; js < 4; ++js) {
            f4v p0 = s0acc[js] - mrun;
            f4v p1 = s1acc[js] - mrun;
#pragma unroll
            for (int r = 0; r < 4; ++r) {
                p0[r] = __builtin_amdgcn_exp2f(p0[r]);
                p1[r] = __builtin_amdgcn_exp2f(p1[r]);
            }
            l4 += p0 + p1;
            __asm__("v_cvt_pk_bf16_f32 %0, %1, %2" : "=v"(pk0[js*2])   : "v"(p0[0]), "v"(p0[1]));
            __asm__("v_cvt_pk_bf16_f32 %0, %1, %2" : "=v"(pk0[js*2+1]) : "v"(p0[2]), "v"(p0[3]));
            __asm__("v_cvt_pk_bf16_f32 %0, %1, %2" : "=v"(pk1[js*2])   : "v"(p1[0]), "v"(p1[1]));
            __asm__("v_cvt_pk_bf16_f32 %0, %1, %2" : "=v"(pk1[js*2+1]) : "v"(p1[2]), "v"(p1[3]));
        }

        __syncthreads();  // (C) all waves done reading K0/K1

#pragma unroll
        for (int js = 0; js < 4; ++js) {
            *(uint2*)(K0 + myrow + js * 16 + quad * 4) = make_uint2(pk0[js*2], pk0[js*2+1]);
            *(uint2*)(K1 + myrow + js * 16 + quad * 4) = make_uint2(pk1[js*2], pk1[js*2+1]);
        }
        __syncthreads();  // (D)

        // O += P0.V0 + P1.V1 : A[m=t][k=s] from K0/K1, B[n=d][k=s] from V0/V1
#pragma unroll
        for (int ks = 0; ks < 2; ++ks) {
            s8v p0 = *(const s8v*)(K0 + myrow + ks * 32 + quad * 8);
            s8v p1 = *(const s8v*)(K1 + myrow + ks * 32 + quad * 8);
#pragma unroll
            for (int jd = 0; jd < 4; ++jd) {
                s8v v0_ = *(const s8v*)(V0 + (jd * 16 + col16) * PT + ks * 32 + quad * 8);
                s8v v1_ = *(const s8v*)(V1 + (jd * 16 + col16) * PT + ks * 32 + quad * 8);
                oacc[jd] = __builtin_amdgcn_mfma_f32_16x16x32_bf16(p0, v0_, oacc[jd], 0, 0, 0);
                oacc[jd] = __builtin_amdgcn_mfma_f32_16x16x32_bf16(p1, v1_, oacc[jd], 0, 0, 0);
            }
        }
    }

    // epilogue: reduce row-sum partials (4 s-slots, then cross-quad),
    // normalize and write bf16
    float lr = l4[0] + l4[1] + l4[2] + l4[3];
    lr += __shfl_xor(lr, 16);
    lr += __shfl_xor(lr, 32);
    const float inv = 1.0f / lr;
    float invr[4];
#pragma unroll
    for (int r = 0; r < 4; ++r) invr[r] = __shfl(inv, quad * 4 + r);
#pragma unroll
    for (int r = 0; r < 4; ++r) {
        const int t = t0 + w * 16 + quad * 4 + r;
#pragma unroll
        for (int jd = 0; jd < 4; ++jd)
            O[(size_t)(b_ * TT + t) * EE + h * HDIM + jd * 16 + col16] =
                f2bf(oacc[jd][r] * invr[r]);
    }
}

// ---------------------------------------------------------------------------
extern "C" void kernel_launch(void* const* d_in, const int* in_sizes, int n_in,
                              void* d_out, int out_size, void* d_ws, size_t ws_size,
                              hipStream_t stream)
{
    (void)in_sizes; (void)n_in; (void)out_size; (void)ws_size;

    const float* x    = (const float*)d_in[0];
    const float* mask = (const float*)d_in[1];
    const float* Wq   = (const float*)d_in[2];
    const float* bq   = (const float*)d_in[3];
    const float* Wk   = (const float*)d_in[4];
    const float* bk   = (const float*)d_in[5];
    const float* Wv   = (const float*)d_in[6];
    const float* bv   = (const float*)d_in[7];
    const float* Wo   = (const float*)d_in[8];
    const float* bo   = (const float*)d_in[9];
    float* out = (float*)d_out;

    // workspace carve (ushort units): 42M ushorts = 84 MB
    unsigned short* xb  = (unsigned short*)d_ws;
    unsigned short* wqb = xb  + (size_t)MROWS * EE;          // 4M
    unsigned short* wkb = wqb + (size_t)EE * EE;             // 1M
    unsigned short* wvb = wkb + (size_t)2 * EE * EE;         // 2M
    unsigned short* wob = wvb + (size_t)2 * EE * EE;         // 2M
    unsigned short* mb  = wob + (size_t)EE * EE;             // 1M
    unsigned short* qp  = mb  + (size_t)BB * TT * TT;        // 4M
    unsigned short* kp  = qp  + (size_t)MROWS * EE;          // 4M
    unsigned short* vt  = kp  + (size_t)BB * HH * SS * HDIM; // 8M
    unsigned short* ao  = vt  + (size_t)BB * HH * SS * HDIM; // 8M

    dim3 blk(256);

    // fused fp32->bf16 conversion (x + 4 weights + mask; mask *= log2e)
    cvt6_kernel<<<4096, blk, 0, stream>>>(x, Wq, Wk, Wv, Wo, mask,
                                          xb, wqb, wkb, wvb, wob, mb);
    // fused Q+K projection (Q scaled by SCALE*log2e for exp2-domain softmax)
    gemm_qk_kernel<<<dim3(32, 24), blk, 0, stream>>>(xb, wqb, wkb, bq, bk, qp, kp);
    // V projection computed transposed (A=Wv, W=x) -> V^T [B,H,HD,S]
    gemm_mfma_kernel<2, 0, EE, MROWS><<<dim3(16, 32), blk, 0, stream>>>(
        wvb, xb, bv, vt, 1.0f);
    // attention (4 blocks/CU fully-resident, mask-in-C, defer-max, cvt_pk)
    attn_mfma3_kernel<<<dim3(1024), blk, 0, stream>>>(qp, kp, vt, mb, ao);
    // output projection -> fp32 out
    gemm_mfma_kernel<0, 1, EE, EE><<<dim3(32, 8), blk, 0, stream>>>(
        ao, wob, bo, out, 1.0f);
}